// Round 22
// baseline (20823.753 us; speedup 1.0000x reference)
//
#include <hip/hip_runtime.h>
#include <hip/hip_fp16.h>
#include <math.h>

#define Bz 16
#define Tz 1024
#define Ez 768
#define E3 2304
#define Vz 50257
#define NBK 256          // 256 blocks: layer (2) x batch-group (2) x col-group (64)
#define LN_EPS 1e-5f
#define VEC (Bz*Ez)      // 12288 floats per full h vector
#define VECW 6144        // packed fp16: u32 words per full h vector
#define EP 772           // padded LDS row stride (fp32)
#define BS 8             // batches per block
#define CW 12            // columns per block
#define WROWW 384        // u32 words per fp16 weight row

__device__ __forceinline__ float dot4acc(float acc, float4 w, float4 h){
  acc = fmaf(w.x,h.x,acc); acc = fmaf(w.y,h.y,acc);
  acc = fmaf(w.z,h.z,acc); acc = fmaf(w.w,h.w,acc);
  return acc;
}
__device__ __forceinline__ float sigm(float x){ return 1.0f/(1.0f+expf(-x)); }

__device__ __forceinline__ unsigned pack2(float a, float b){
  __half2 h = __floats2half2_rn(a, b);
  union{__half2 h2; unsigned u;} cv; cv.h2 = h; return cv.u;
}
__device__ __forceinline__ float2 unpack2(unsigned u){
  union{unsigned u; __half2 h2;} cv; cv.u = u;
  return __half22float2(cv.h2);
}
__device__ __forceinline__ float4 up4(uint2 u){
  const float2 a = unpack2(u.x), b = unpack2(u.y);
  return make_float4(a.x, a.y, b.x, b.y);
}

// ---- Staging envelope (empirical): scalar 32-bit relaxed-atomic loads with
// immediate LDS stores, <=4 outstanding per body. Byte-identical to R21. ----

// Stage this block's 8 batches of one h vector: 3072 words, 6/thread.
__device__ __forceinline__ void stage8(const unsigned* __restrict__ src,
                                       float (*dst)[EP], int tid){
#pragma unroll
  for (int k=0;k<2;k++){
    const int u0 = tid + k*1536;
    const int u1 = u0 + 512;
    const int u2 = u0 + 1024;
    const unsigned a0 = __hip_atomic_load(src+u0, __ATOMIC_RELAXED, __HIP_MEMORY_SCOPE_AGENT);
    const unsigned a1 = __hip_atomic_load(src+u1, __ATOMIC_RELAXED, __HIP_MEMORY_SCOPE_AGENT);
    const unsigned a2 = __hip_atomic_load(src+u2, __ATOMIC_RELAXED, __HIP_MEMORY_SCOPE_AGENT);
    {const int b=u0/384, c=(u0-b*384)<<1; const float2 f=unpack2(a0); dst[b][c]=f.x; dst[b][c+1]=f.y;}
    {const int b=u1/384, c=(u1-b*384)<<1; const float2 f=unpack2(a1); dst[b][c]=f.x; dst[b][c+1]=f.y;}
    {const int b=u2/384, c=(u2-b*384)<<1; const float2 f=unpack2(a2); dst[b][c]=f.x; dst[b][c+1]=f.y;}
  }
}

__device__ __forceinline__ void zero8(float (*dst)[EP], int tid){
#pragma unroll
  for (int k=0;k<6;k++){
    const int u = tid + (k<<9);
    const int b = u/384, c = (u-b*384)<<1;
    dst[b][c] = 0.f; dst[b][c+1] = 0.f;
  }
}

// 6 rows/wave on waves 0-5 (36 rows total), 8 batches (bb -> 2 each).
// Weights: packed fp16 rows (uint2 = 4 values); operands: fp32 LDS.
__device__ __forceinline__ void mm6(const float (*V)[EP],
                                    const unsigned* const (&wRow)[6],
                                    float (*gOut)[9],
                                    int wv, int kq, int bb){
  float acc[6][2];
#pragma unroll
  for (int r=0;r<6;r++){ acc[r][0]=0.f; acc[r][1]=0.f; }
#pragma unroll 4
  for (int j=0;j<12;j++){
    const int kk  = (j<<6) + (kq<<2);     // fp32 operand index
    const int kk2 = (j<<5) + (kq<<1);     // u32 weight-word index
    float4 w4[6];
#pragma unroll
    for (int r=0;r<6;r++) w4[r] = up4(*(const uint2*)(wRow[r] + kk2));
#pragma unroll
    for (int bi=0;bi<2;bi++){
      const float4 hv = *(const float4*)&V[bb*2+bi][kk];
#pragma unroll
      for (int r=0;r<6;r++) acc[r][bi] = dot4acc(acc[r][bi], w4[r], hv);
    }
  }
#pragma unroll
  for (int r=0;r<6;r++)
#pragma unroll
    for (int bi=0;bi<2;bi++){
      float a = acc[r][bi];
      a += __shfl_xor(a,1); a += __shfl_xor(a,2);
      a += __shfl_xor(a,4); a += __shfl_xor(a,8);
      acc[r][bi]=a;
    }
  if (kq==0){
#pragma unroll
    for (int r=0;r<6;r++)
#pragma unroll
      for (int bi=0;bi<2;bi++) gOut[wv*6+r][bb*2+bi] = acc[r][bi];
  }
}

// ---------------------------------------------------------------------------
// Pre-kernel: convert Wih/Whh (both layers) to packed fp16.
// Layout: [(L*2+mat)*E3 + row] * 384 u32; mat 0=ih, 1=hh.
// ---------------------------------------------------------------------------
__global__ __launch_bounds__(256) void conv_w16(
    const float* __restrict__ Wih, const float* __restrict__ Whh,
    unsigned* __restrict__ w16)
{
  const size_t total = (size_t)4*E3*WROWW;
  const size_t gid = (size_t)blockIdx.x*256 + threadIdx.x;
  for (size_t u = gid; u < total; u += (size_t)1024*256){
    const int gr = (int)(u/WROWW), w = (int)(u - (size_t)gr*WROWW);
    const int L = gr/(2*E3), rem = gr - L*2*E3;
    const int mat = rem/E3, row = rem - mat*E3;
    const float* src = (mat ? Whh : Wih) + (size_t)L*E3*Ez + (size_t)row*Ez + (w<<1);
    w16[u] = pack2(src[0], src[1]);
  }
}

// ---------------------------------------------------------------------------
// Persistent cooperative scan = R21 (pipelined, 2D batch x col split),
// with fp16 WEIGHTS (operands stay fp32 in LDS). Per-XCD weight footprint
// 3.54 -> 1.77 MB: L2-resident, removing the ~5.1 MB/step refetch that sat
// on the pipelined critical path (R21: dur == FETCH/402GB/s again).
// ---------------------------------------------------------------------------
__global__ __launch_bounds__(512) void gru_scan(
    const int* __restrict__ idx, const float* __restrict__ wte,
    const unsigned* __restrict__ w16,
    const float* __restrict__ bih, const float* __restrict__ bhh,
    unsigned* __restrict__ h0g, unsigned* __restrict__ h1g,
    float* __restrict__ h1f,
    unsigned* __restrict__ flags, unsigned* __restrict__ go)
{
  __shared__ float bufX[BS][EP];    // E-phase input (x or h0)
  __shared__ float bufH[BS][EP];    // C-phase own-layer h_prev
  __shared__ float gatesI[36][9];   // gi (from E, used next C)
  __shared__ float gatesG[36][9];   // gh (computed in C)
  __shared__ float biasS[72];
  __shared__ float hprev[BS][CW];   // own (batch,col) h, exact fp32

  const int tid = threadIdx.x, bx = blockIdx.x;
  const int L = bx>>7, sub = bx&127;
  const int bg = sub>>6, cg = sub&63;
  const int c0 = cg*CW, b0 = bg*BS;
  const int wv = tid>>6, lane = tid&63, kq = lane&15, bb = lane>>4;

  // waves 0-5: 6 rows each; row m -> gate g=m/12, col cc=m%12
  const unsigned* wiRow[6];
  const unsigned* whRow[6];
#pragma unroll
  for (int r=0;r<6;r++){
    const int m = (wv<6 ? wv : 0)*6 + r, g = m/12, cc = m - g*12;
    const int grow = g*Ez + c0 + cc;
    wiRow[r] = w16 + (size_t)((L*2+0)*E3 + grow)*WROWW;
    whRow[r] = w16 + (size_t)((L*2+1)*E3 + grow)*WROWW;
  }
  if (tid<72){
    const int mat = tid/36, mm = tid%36, g = mm/12, cc = mm-g*12;
    biasS[tid] = (mat ? bhh : bih)[L*E3 + g*Ez + c0 + cc];
  }
  if (tid<96) hprev[tid&7][tid>>3] = 0.f;

  // ---- prologue: L0 precomputes gi0 for x(0) ----
  if (L==0){
#pragma unroll
    for (int k=0;k<3;k++){
      const int i4 = tid + (k<<9);
      const int b = i4/192, c4 = i4 - b*192;
      const int row = idx[(b0+b)*Tz];
      *(float4*)&bufX[b][c4<<2] = *(const float4*)(wte + (size_t)row*Ez + (c4<<2));
    }
    __syncthreads();
    if (wv<6) mm6(bufX, wiRow, gatesI, wv, kq, bb);
  }
  __syncthreads();

  for (int s=0; s<=Tz+1; ++s){
    // ---- grid wait (two-level relay + replicated go lines) ----
    if (s>0){
      const unsigned tgt = (unsigned)s;
      if (bx==0){
        if (tid<64){
          const unsigned* f = flags + (tid<<2);
          for(;;){
            const unsigned a0 = __hip_atomic_load(f+0, __ATOMIC_RELAXED, __HIP_MEMORY_SCOPE_AGENT);
            const unsigned a1 = __hip_atomic_load(f+1, __ATOMIC_RELAXED, __HIP_MEMORY_SCOPE_AGENT);
            const unsigned a2 = __hip_atomic_load(f+2, __ATOMIC_RELAXED, __HIP_MEMORY_SCOPE_AGENT);
            const unsigned a3 = __hip_atomic_load(f+3, __ATOMIC_RELAXED, __HIP_MEMORY_SCOPE_AGENT);
            const int ok = (a0>=tgt) & (a1>=tgt) & (a2>=tgt) & (a3>=tgt);
            if (__all(ok)) break;
            __builtin_amdgcn_s_sleep(1);
          }
          __hip_atomic_store(go + (tid<<5), tgt,
                             __ATOMIC_RELAXED, __HIP_MEMORY_SCOPE_AGENT);
        }
      } else {
        if (tid==0){
          const unsigned* gp = go + ((bx&63)<<5);
          while (__hip_atomic_load(gp, __ATOMIC_RELAXED, __HIP_MEMORY_SCOPE_AGENT) < tgt)
            __builtin_amdgcn_s_sleep(2);
        }
      }
      __syncthreads();
    }

    // ---- critical phase C ----
    const bool activeC = (L==0) ? (s<Tz) : (s>=2);
    if (activeC){
      if (L==0){
        if (s==0) zero8(bufH, tid);
        else      stage8(h0g + (size_t)((s-1)%3)*VECW + bg*3072, bufH, tid);
      } else {
        if (s==2) zero8(bufH, tid);
        else      stage8(h1g + (size_t)((s-1)&1)*VECW + bg*3072, bufH, tid);
      }
      __syncthreads();
      if (wv<6) mm6(bufH, whRow, gatesG, wv, kq, bb);
      __syncthreads();

      if (tid<48){
        const int b = tid&7, j = tid>>3;     // pair j: cols 2j, 2j+1 (j<6)
        float hv2[2];
#pragma unroll
        for (int e=0;e<2;e++){
          const int cc = 2*j+e;
          const float gir = gatesI[cc    ][b] + biasS[cc];
          const float giz = gatesI[12+cc][b] + biasS[12+cc];
          const float gin = gatesI[24+cc][b] + biasS[24+cc];
          const float ghr = gatesG[cc    ][b] + biasS[36+cc];
          const float ghz = gatesG[12+cc][b] + biasS[48+cc];
          const float ghn = gatesG[24+cc][b] + biasS[60+cc];
          const float r = sigm(gir+ghr);
          const float z = sigm(giz+ghz);
          const float n = tanhf(fmaf(r, ghn, gin));
          const float hp = hprev[b][cc];     // exact fp32 private state
          hv2[e] = fmaf(z, hp - n, n);
          hprev[b][cc] = hv2[e];
        }
        unsigned* hOutW = (L==0) ? (h0g + (size_t)(s%3)*VECW)
                                 : (h1g + (size_t)(s&1)*VECW);
        const unsigned pk = pack2(hv2[0], hv2[1]);
        __hip_atomic_store(hOutW + (b0+b)*384 + cg*6 + j, pk,
                           __ATOMIC_RELAXED, __HIP_MEMORY_SCOPE_AGENT);
        if (L==1 && s==Tz+1){                // h1(Tz-1) -> fp32 for LN
          h1f[(b0+b)*Ez + c0 + 2*j    ] = hv2[0];
          h1f[(b0+b)*Ez + c0 + 2*j + 1] = hv2[1];
        }
      }
    }

    // ---- arrive: drain publish stores, then flag ----
    __syncthreads();
    if (tid==0)
      __hip_atomic_store(flags + bx, (unsigned)(s+1),
                         __ATOMIC_RELAXED, __HIP_MEMORY_SCOPE_AGENT);

    // ---- overlap phase E ----
    const bool activeE = (L==0) ? (s < Tz-1) : (s>=1 && s<=Tz);
    if (activeE){
      if (L==0){
#pragma unroll
        for (int k=0;k<3;k++){
          const int i4 = tid + (k<<9);
          const int b = i4/192, c4 = i4 - b*192;
          const int row = idx[(b0+b)*Tz + (s+1)];
          *(float4*)&bufX[b][c4<<2] = *(const float4*)(wte + (size_t)row*Ez + (c4<<2));
        }
      } else {
        // h0(s-1): 2-barrier-old by consumption; h0 triple-buffered.
        stage8(h0g + (size_t)((s-1)%3)*VECW + bg*3072, bufX, tid);
      }
      __syncthreads();
      if (wv<6) mm6(bufX, wiRow, gatesI, wv, kq, bb);
    }
  }
}

// LayerNorm of final h1 (fp32) -> ln
__global__ __launch_bounds__(256) void finalize_ln(
    const float* __restrict__ h1, const float* __restrict__ g,
    float* __restrict__ ln)
{
  const int tid=threadIdx.x, wv=tid>>6, lane=tid&63;
  for (int b=wv; b<Bz; b+=4){
    float sum=0.f;
    for (int c=lane;c<Ez;c+=64) sum += h1[b*Ez+c];
#pragma unroll
    for (int off=32; off; off>>=1) sum += __shfl_xor(sum, off);
    const float mu = sum/(float)Ez;
    float s2=0.f;
    for (int c=lane;c<Ez;c+=64){ const float d=h1[b*Ez+c]-mu; s2=fmaf(d,d,s2); }
#pragma unroll
    for (int off=32; off; off>>=1) s2 += __shfl_xor(s2, off);
    const float inv = rsqrtf(s2/(float)Ez + LN_EPS);
    for (int c=lane;c<Ez;c+=64) ln[b*Ez+c] = (h1[b*Ez+c]-mu)*inv*g[c];
  }
}

// logits[b,v] = dot(ln[b,:], wte[v,:]) ; 64 rows per block, 16 rows per wave.
__global__ __launch_bounds__(256) void lm_head(
    const float* __restrict__ ln, const float* __restrict__ wte,
    float* __restrict__ out)
{
  __shared__ float sLn[Bz][EP];
  const int tid=threadIdx.x;
  for (int i4=tid; i4<Bz*Ez/4; i4+=256){
    const int b = i4/(Ez/4), c = (i4 - b*(Ez/4))<<2;
    *(float4*)(&sLn[b][c]) = *(const float4*)(ln + b*Ez + c);
  }
  __syncthreads();
  const int wv=tid>>6, lane=tid&63, rr=lane>>4, cl=lane&15;
  const int vbase = blockIdx.x*64 + wv*16 + rr;
  float acc[4][16];
#pragma unroll
  for (int k=0;k<4;k++)
#pragma unroll
    for (int b=0;b<16;b++) acc[k][b]=0.f;

  for (int j=0;j<12;j++){
    const int c = (cl<<2) + (j<<6);
    float4 w4[4];
#pragma unroll
    for (int k=0;k<4;k++){
      const int v = vbase + 4*k;
      if (v < Vz) w4[k] = *(const float4*)(wte + (size_t)v*Ez + c);
      else { w4[k].x=w4[k].y=w4[k].z=w4[k].w=0.f; }
    }
#pragma unroll
    for (int b=0;b<16;b++){
      const float4 hv = *(const float4*)(&sLn[b][c]);
#pragma unroll
      for (int k=0;k<4;k++) acc[k][b] = dot4acc(acc[k][b], w4[k], hv);
    }
  }
#pragma unroll
  for (int off=1; off<16; off<<=1)
#pragma unroll
    for (int k=0;k<4;k++)
#pragma unroll
      for (int b=0;b<16;b++) acc[k][b] += __shfl_xor(acc[k][b], off);

  if (cl==0){
#pragma unroll
    for (int k=0;k<4;k++){
      const int v = vbase + 4*k;
      if (v < Vz){
#pragma unroll
        for (int b=0;b<16;b++) out[(size_t)b*Vz + v] = acc[k][b];
      }
    }
  }
}

extern "C" void kernel_launch(void* const* d_in, const int* in_sizes, int n_in,
                              void* d_out, int out_size, void* d_ws, size_t ws_size,
                              hipStream_t stream) {
  const int*   idx = (const int*)  d_in[0];
  const float* wte = (const float*)d_in[1];
  const float* Wih = (const float*)d_in[2];
  const float* bih = (const float*)d_in[3];
  const float* Whh = (const float*)d_in[4];
  const float* bhh = (const float*)d_in[5];
  const float* g   = (const float*)d_in[6];
  float* out = (float*)d_out;

  unsigned* flags = (unsigned*)d_ws;            // words [0,256)
  unsigned* go    = (unsigned*)d_ws + 512;      // words [512,2560): 64 lines
  unsigned* h0g   = (unsigned*)d_ws + 4096;     // 3 x 6144 words (triple buf)
  unsigned* h1g   = h0g + 3*VECW;               // 2 x 6144 words
  float*    h1f   = (float*)(h1g + 2*VECW);     // B*E fp32 final h1
  float*    ln    = h1f + VEC;                  // B*E fp32
  unsigned* w16   = (unsigned*)d_ws + 65536;    // 4*2304*384 words (13.5 MB)

  (void)hipMemsetAsync(d_ws, 0, 16384, stream); // reset flags + go lines

  conv_w16<<<1024, 256, 0, stream>>>(Wih, Whh, w16);

  void* args[] = {(void*)&idx,(void*)&wte,(void*)&w16,(void*)&bih,(void*)&bhh,
                  (void*)&h0g,(void*)&h1g,(void*)&h1f,(void*)&flags,(void*)&go};
  (void)hipLaunchCooperativeKernel((void*)gru_scan, dim3(NBK), dim3(512), args, 0, stream);

  finalize_ln<<<1, 256, 0, stream>>>(h1f, g, ln);
  lm_head<<<786, 256, 0, stream>>>(ln, wte, out);
}

// Round 23
// 11933.256 us; speedup vs baseline: 1.7450x; 1.7450x over previous
//
#include <hip/hip_runtime.h>
#include <hip/hip_fp16.h>
#include <math.h>

#define Bz 16
#define Tz 1024
#define Ez 768
#define E3 2304
#define Vz 50257
#define NBK 256          // 256 blocks: layer (2) x batch-group (2) x col-group (64)
#define LN_EPS 1e-5f
#define VEC (Bz*Ez)      // 12288 floats per full h vector
#define VECW 6144        // packed fp16: u32 words per full h vector
#define EP 772           // padded LDS row stride (fp32)
#define BS 8             // batches per block
#define CW 12            // columns per block

__device__ __forceinline__ float dot4acc(float acc, float4 w, float4 h){
  acc = fmaf(w.x,h.x,acc); acc = fmaf(w.y,h.y,acc);
  acc = fmaf(w.z,h.z,acc); acc = fmaf(w.w,h.w,acc);
  return acc;
}
__device__ __forceinline__ float sigm(float x){ return 1.0f/(1.0f+expf(-x)); }

__device__ __forceinline__ unsigned pack2(float a, float b){
  __half2 h = __floats2half2_rn(a, b);
  union{__half2 h2; unsigned u;} cv; cv.h2 = h; return cv.u;
}
__device__ __forceinline__ float2 unpack2(unsigned u){
  union{unsigned u; __half2 h2;} cv; cv.u = u;
  return __half22float2(cv.h2);
}

// ---- Staging envelope (empirical): scalar 32-bit relaxed-atomic loads with
// immediate LDS stores, <=4 outstanding per body. Shapes proven R13/R15/R21. ----

// One vector slice (8 batches, 3072 words), 6 words/thread, 2 bodies of 3.
__device__ __forceinline__ void stage8(const unsigned* __restrict__ src,
                                       float (*dst)[EP], int tid){
#pragma unroll
  for (int k=0;k<2;k++){
    const int u0 = tid + k*1536;
    const int u1 = u0 + 512;
    const int u2 = u0 + 1024;
    const unsigned a0 = __hip_atomic_load(src+u0, __ATOMIC_RELAXED, __HIP_MEMORY_SCOPE_AGENT);
    const unsigned a1 = __hip_atomic_load(src+u1, __ATOMIC_RELAXED, __HIP_MEMORY_SCOPE_AGENT);
    const unsigned a2 = __hip_atomic_load(src+u2, __ATOMIC_RELAXED, __HIP_MEMORY_SCOPE_AGENT);
    {const int b=u0/384, c=(u0-b*384)<<1; const float2 f=unpack2(a0); dst[b][c]=f.x; dst[b][c+1]=f.y;}
    {const int b=u1/384, c=(u1-b*384)<<1; const float2 f=unpack2(a1); dst[b][c]=f.x; dst[b][c+1]=f.y;}
    {const int b=u2/384, c=(u2-b*384)<<1; const float2 f=unpack2(a2); dst[b][c]=f.x; dst[b][c+1]=f.y;}
  }
}

// Two vector slices interleaved (R15 stage_two shape): 3 bodies of 4.
__device__ __forceinline__ void stage8x2(const unsigned* __restrict__ srcX,
                                         float (*dstX)[EP],
                                         const unsigned* __restrict__ srcH,
                                         float (*dstH)[EP], int tid){
#pragma unroll
  for (int k=0;k<3;k++){
    const int u0 = tid + (k<<10);
    const int u1 = u0 + 512;
    const unsigned x0 = __hip_atomic_load(srcX+u0, __ATOMIC_RELAXED, __HIP_MEMORY_SCOPE_AGENT);
    const unsigned x1 = __hip_atomic_load(srcX+u1, __ATOMIC_RELAXED, __HIP_MEMORY_SCOPE_AGENT);
    const unsigned h0 = __hip_atomic_load(srcH+u0, __ATOMIC_RELAXED, __HIP_MEMORY_SCOPE_AGENT);
    const unsigned h1 = __hip_atomic_load(srcH+u1, __ATOMIC_RELAXED, __HIP_MEMORY_SCOPE_AGENT);
    const int b0=u0/384, c0_=(u0-b0*384)<<1;
    const int b1=u1/384, c1_=(u1-b1*384)<<1;
    {const float2 f=unpack2(x0); dstX[b0][c0_]=f.x; dstX[b0][c0_+1]=f.y;}
    {const float2 f=unpack2(x1); dstX[b1][c1_]=f.x; dstX[b1][c1_+1]=f.y;}
    {const float2 f=unpack2(h0); dstH[b0][c0_]=f.x; dstH[b0][c0_+1]=f.y;}
    {const float2 f=unpack2(h1); dstH[b1][c1_]=f.x; dstH[b1][c1_+1]=f.y;}
  }
}

__device__ __forceinline__ void zero8(float (*dst)[EP], int tid){
#pragma unroll
  for (int k=0;k<6;k++){
    const int u = tid + (k<<9);
    const int b = u/384, c = (u-b*384)<<1;
    dst[b][c] = 0.f; dst[b][c+1] = 0.f;
  }
}

// 9 rows per wave (wave-group row base wv4*9), 8 batches (bb -> 2 each).
__device__ __forceinline__ void mm9(const float (*V)[EP],
                                    const float* const (&wRow)[9],
                                    float (*gOut)[9],
                                    int wv4, int kq, int bb){
  float acc[9][2];
#pragma unroll
  for (int r=0;r<9;r++){ acc[r][0]=0.f; acc[r][1]=0.f; }
#pragma unroll 4
  for (int j=0;j<12;j++){
    const int kk = (j<<6) + (kq<<2);
    float4 w4[9];
#pragma unroll
    for (int r=0;r<9;r++) w4[r] = *(const float4*)(wRow[r] + kk);
#pragma unroll
    for (int bi=0;bi<2;bi++){
      const float4 hv = *(const float4*)&V[bb*2+bi][kk];
#pragma unroll
      for (int r=0;r<9;r++) acc[r][bi] = dot4acc(acc[r][bi], w4[r], hv);
    }
  }
#pragma unroll
  for (int r=0;r<9;r++)
#pragma unroll
    for (int bi=0;bi<2;bi++){
      float a = acc[r][bi];
      a += __shfl_xor(a,1); a += __shfl_xor(a,2);
      a += __shfl_xor(a,4); a += __shfl_xor(a,8);
      acc[r][bi]=a;
    }
  if (kq==0){
#pragma unroll
    for (int r=0;r<9;r++)
#pragma unroll
      for (int bi=0;bi<2;bi++) gOut[wv4*9+r][bb*2+bi] = acc[r][bi];
  }
}

// ---------------------------------------------------------------------------
// Persistent cooperative scan, FUSED single phase per step:
//  Waves 0-3 compute gatesG = Whh . h_own(prev) while waves 4-7 compute
//  gatesI = Wih . input(next) CONCURRENTLY (was: two serial 6-wave passes).
//  gatesI ping-pongs: written at step s, consumed at s+1.
//  L0 at s: h0(s) = f(gatesI[from x(s)], gatesG[h0(s-1)], hprev). Post-flag:
//    cached prefetch x(s+2) only (~0.3us < relay latency).
//  L1 (lag 2) at s: h1(s-2); stages h1(s-3) + h0(s-1) in one 4-wide pass.
//  h0 triple-buffered, h1 double; fp32 weights (fp16 weights proven bad twice);
//  barrier = R21 two-level relay verbatim.
// ---------------------------------------------------------------------------
__global__ __launch_bounds__(512) void gru_scan(
    const int* __restrict__ idx, const float* __restrict__ wte,
    const float* __restrict__ Wih, const float* __restrict__ bih,
    const float* __restrict__ Whh, const float* __restrict__ bhh,
    unsigned* __restrict__ h0g, unsigned* __restrict__ h1g,
    float* __restrict__ h1f,
    unsigned* __restrict__ flags, unsigned* __restrict__ go)
{
  __shared__ float bufX[BS][EP];      // gi input: x(s+1) (L0) / h0(s-1) (L1)
  __shared__ float bufH[BS][EP];      // gh input: own-layer h_prev
  __shared__ float gatesG[36][9];     // gh (this step)
  __shared__ float gatesI[2][36][9];  // gi ping-pong (s&1 = write slot)
  __shared__ float biasS[72];
  __shared__ float hprev[BS][CW];     // own (batch,col) h, exact fp32

  const int tid = threadIdx.x, bx = blockIdx.x;
  const int L = bx>>7, sub = bx&127;
  const int bg = sub>>6, cg = sub&63;
  const int c0 = cg*CW, b0 = bg*BS;
  const int wv = tid>>6, lane = tid&63, kq = lane&15, bb = lane>>4;
  const int wv4 = wv & 3;

  const float* WihL = Wih + (size_t)L*E3*Ez;
  const float* WhhL = Whh + (size_t)L*E3*Ez;

  // waves 0-3 -> Whh rows (gatesG); waves 4-7 -> Wih rows (gatesI).
  const float* wRow[9];
  {
    const float* Wb = (wv < 4) ? WhhL : WihL;
#pragma unroll
    for (int r=0;r<9;r++){
      const int m = wv4*9 + r, g = m/12, cc = m - g*12;
      wRow[r] = Wb + (size_t)(g*Ez + c0 + cc)*Ez;
    }
  }
  if (tid<72){
    const int mat = tid/36, mm = tid%36, g = mm/12, cc = mm-g*12;
    biasS[tid] = (mat ? bhh : bih)[L*E3 + g*Ez + c0 + cc];
  }
  if (tid<96) hprev[tid&7][tid>>3] = 0.f;

  // ---- prologue (L0): gatesI[1] <- Wih . x(0); then load x(1) ----
  if (L==0){
#pragma unroll
    for (int k=0;k<3;k++){
      const int i4 = tid + (k<<9);
      const int b = i4/192, c4 = i4 - b*192;
      const int row = idx[(b0+b)*Tz];
      *(float4*)&bufX[b][c4<<2] = *(const float4*)(wte + (size_t)row*Ez + (c4<<2));
    }
    __syncthreads();
    if (wv>=4) mm9(bufX, wRow, gatesI[1], wv4, kq, bb);
    __syncthreads();
#pragma unroll
    for (int k=0;k<3;k++){
      const int i4 = tid + (k<<9);
      const int b = i4/192, c4 = i4 - b*192;
      const int row = idx[(b0+b)*Tz + 1];
      *(float4*)&bufX[b][c4<<2] = *(const float4*)(wte + (size_t)row*Ez + (c4<<2));
    }
  }
  __syncthreads();

  for (int s=0; s<=Tz+1; ++s){
    // ---- grid wait (two-level relay + replicated go lines, verbatim) ----
    if (s>0){
      const unsigned tgt = (unsigned)s;
      if (bx==0){
        if (tid<64){
          const unsigned* f = flags + (tid<<2);
          for(;;){
            const unsigned a0 = __hip_atomic_load(f+0, __ATOMIC_RELAXED, __HIP_MEMORY_SCOPE_AGENT);
            const unsigned a1 = __hip_atomic_load(f+1, __ATOMIC_RELAXED, __HIP_MEMORY_SCOPE_AGENT);
            const unsigned a2 = __hip_atomic_load(f+2, __ATOMIC_RELAXED, __HIP_MEMORY_SCOPE_AGENT);
            const unsigned a3 = __hip_atomic_load(f+3, __ATOMIC_RELAXED, __HIP_MEMORY_SCOPE_AGENT);
            const int ok = (a0>=tgt) & (a1>=tgt) & (a2>=tgt) & (a3>=tgt);
            if (__all(ok)) break;
            __builtin_amdgcn_s_sleep(1);
          }
          __hip_atomic_store(go + (tid<<5), tgt,
                             __ATOMIC_RELAXED, __HIP_MEMORY_SCOPE_AGENT);
        }
      } else {
        if (tid==0){
          const unsigned* gp = go + ((bx&63)<<5);
          while (__hip_atomic_load(gp, __ATOMIC_RELAXED, __HIP_MEMORY_SCOPE_AGENT) < tgt)
            __builtin_amdgcn_s_sleep(2);
        }
      }
      __syncthreads();
    }

    // ---- activity windows ----
    const bool gG = (L==0) ? (s<=Tz-1) : (s>=2);               // gh + nonlin
    const bool gI = (L==0) ? (s<=Tz-2) : (s>=1 && s<=Tz);      // gi for next step

    // ---- stage ----
    if (L==0){
      if (s==0)            zero8(bufH, tid);
      else if (s<=Tz-1)    stage8(h0g + (size_t)((s-1)%3)*VECW + bg*3072, bufH, tid);
      // bufX holds x(s+1), prefetched (cached)
    } else {
      const unsigned* x_src = h0g + (size_t)((s-1)%3)*VECW + bg*3072;   // h0(s-1)
      const unsigned* h_src = h1g + (size_t)((s-1)&1)*VECW + bg*3072;   // h1(s-3)
      if (s>=3 && s<=Tz)      stage8x2(x_src, bufX, h_src, bufH, tid);
      else if (s==2)        { stage8(x_src, bufX, tid); zero8(bufH, tid); }
      else if (s==1)          stage8(x_src, bufX, tid);
      else if (s==Tz+1)       stage8(h_src, bufH, tid);
    }
    __syncthreads();

    // ---- fused matmul: waves 0-3 gh, waves 4-7 gi (concurrent) ----
    if (wv<4){ if (gG) mm9(bufH, wRow, gatesG,        wv4, kq, bb); }
    else     { if (gI) mm9(bufX, wRow, gatesI[s&1],   wv4, kq, bb); }
    __syncthreads();

    // ---- nonlinearity + publish (48 threads: 8 b x 6 col-pairs) ----
    if (gG && tid<48){
      const int b = tid&7, j = tid>>3;
      float hv2[2];
#pragma unroll
      for (int e=0;e<2;e++){
        const int cc = 2*j+e;
        const float gir = gatesI[(s-1)&1][cc    ][b] + biasS[cc];
        const float giz = gatesI[(s-1)&1][12+cc][b] + biasS[12+cc];
        const float gin = gatesI[(s-1)&1][24+cc][b] + biasS[24+cc];
        const float ghr = gatesG[cc    ][b] + biasS[36+cc];
        const float ghz = gatesG[12+cc][b] + biasS[48+cc];
        const float ghn = gatesG[24+cc][b] + biasS[60+cc];
        const float r = sigm(gir+ghr);
        const float z = sigm(giz+ghz);
        const float n = tanhf(fmaf(r, ghn, gin));
        const float hp = hprev[b][cc];
        hv2[e] = fmaf(z, hp - n, n);
        hprev[b][cc] = hv2[e];
      }
      const unsigned pk = pack2(hv2[0], hv2[1]);
      if (L==0){
        unsigned* hOutW = h0g + (size_t)(s%3)*VECW;
        __hip_atomic_store(hOutW + (b0+b)*384 + cg*6 + j, pk,
                           __ATOMIC_RELAXED, __HIP_MEMORY_SCOPE_AGENT);
      } else {
        unsigned* hOutW = h1g + (size_t)((s-2)&1)*VECW;
        __hip_atomic_store(hOutW + (b0+b)*384 + cg*6 + j, pk,
                           __ATOMIC_RELAXED, __HIP_MEMORY_SCOPE_AGENT);
        if (s==Tz+1){                          // h1(Tz-1) -> fp32 for LN
          h1f[(b0+b)*Ez + c0 + 2*j    ] = hv2[0];
          h1f[(b0+b)*Ez + c0 + 2*j + 1] = hv2[1];
        }
      }
    }

    // ---- arrive: drain publish stores, then flag ----
    __syncthreads();
    if (tid==0)
      __hip_atomic_store(flags + bx, (unsigned)(s+1),
                         __ATOMIC_RELAXED, __HIP_MEMORY_SCOPE_AGENT);

    // ---- post-flag: L0 cached x(s+2) prefetch (fits under relay) ----
    if (L==0 && s<=Tz-3){
#pragma unroll
      for (int k=0;k<3;k++){
        const int i4 = tid + (k<<9);
        const int b = i4/192, c4 = i4 - b*192;
        const int row = idx[(b0+b)*Tz + (s+2)];
        *(float4*)&bufX[b][c4<<2] = *(const float4*)(wte + (size_t)row*Ez + (c4<<2));
      }
    }
  }
}

// LayerNorm of final h1 (fp32) -> ln
__global__ __launch_bounds__(256) void finalize_ln(
    const float* __restrict__ h1, const float* __restrict__ g,
    float* __restrict__ ln)
{
  const int tid=threadIdx.x, wv=tid>>6, lane=tid&63;
  for (int b=wv; b<Bz; b+=4){
    float sum=0.f;
    for (int c=lane;c<Ez;c+=64) sum += h1[b*Ez+c];
#pragma unroll
    for (int off=32; off; off>>=1) sum += __shfl_xor(sum, off);
    const float mu = sum/(float)Ez;
    float s2=0.f;
    for (int c=lane;c<Ez;c+=64){ const float d=h1[b*Ez+c]-mu; s2=fmaf(d,d,s2); }
#pragma unroll
    for (int off=32; off; off>>=1) s2 += __shfl_xor(s2, off);
    const float inv = rsqrtf(s2/(float)Ez + LN_EPS);
    for (int c=lane;c<Ez;c+=64) ln[b*Ez+c] = (h1[b*Ez+c]-mu)*inv*g[c];
  }
}

// logits[b,v] = dot(ln[b,:], wte[v,:]) ; 64 rows per block, 16 rows per wave.
__global__ __launch_bounds__(256) void lm_head(
    const float* __restrict__ ln, const float* __restrict__ wte,
    float* __restrict__ out)
{
  __shared__ float sLn[Bz][EP];
  const int tid=threadIdx.x;
  for (int i4=tid; i4<Bz*Ez/4; i4+=256){
    const int b = i4/(Ez/4), c = (i4 - b*(Ez/4))<<2;
    *(float4*)(&sLn[b][c]) = *(const float4*)(ln + b*Ez + c);
  }
  __syncthreads();
  const int wv=tid>>6, lane=tid&63, rr=lane>>4, cl=lane&15;
  const int vbase = blockIdx.x*64 + wv*16 + rr;
  float acc[4][16];
#pragma unroll
  for (int k=0;k<4;k++)
#pragma unroll
    for (int b=0;b<16;b++) acc[k][b]=0.f;

  for (int j=0;j<12;j++){
    const int c = (cl<<2) + (j<<6);
    float4 w4[4];
#pragma unroll
    for (int k=0;k<4;k++){
      const int v = vbase + 4*k;
      if (v < Vz) w4[k] = *(const float4*)(wte + (size_t)v*Ez + c);
      else { w4[k].x=w4[k].y=w4[k].z=w4[k].w=0.f; }
    }
#pragma unroll
    for (int b=0;b<16;b++){
      const float4 hv = *(const float4*)(&sLn[b][c]);
#pragma unroll
      for (int k=0;k<4;k++) acc[k][b] = dot4acc(acc[k][b], w4[k], hv);
    }
  }
#pragma unroll
  for (int off=1; off<16; off<<=1)
#pragma unroll
    for (int k=0;k<4;k++)
#pragma unroll
      for (int b=0;b<16;b++) acc[k][b] += __shfl_xor(acc[k][b], off);

  if (cl==0){
#pragma unroll
    for (int k=0;k<4;k++){
      const int v = vbase + 4*k;
      if (v < Vz){
#pragma unroll
        for (int b=0;b<16;b++) out[(size_t)b*Vz + v] = acc[k][b];
      }
    }
  }
}

extern "C" void kernel_launch(void* const* d_in, const int* in_sizes, int n_in,
                              void* d_out, int out_size, void* d_ws, size_t ws_size,
                              hipStream_t stream) {
  const int*   idx = (const int*)  d_in[0];
  const float* wte = (const float*)d_in[1];
  const float* Wih = (const float*)d_in[2];
  const float* bih = (const float*)d_in[3];
  const float* Whh = (const float*)d_in[4];
  const float* bhh = (const float*)d_in[5];
  const float* g   = (const float*)d_in[6];
  float* out = (float*)d_out;

  unsigned* flags = (unsigned*)d_ws;            // words [0,256)
  unsigned* go    = (unsigned*)d_ws + 512;      // words [512,2560): 64 lines
  unsigned* h0g   = (unsigned*)d_ws + 4096;     // 3 x 6144 words (triple buf)
  unsigned* h1g   = h0g + 3*VECW;               // 2 x 6144 words
  float*    h1f   = (float*)(h1g + 2*VECW);     // B*E fp32 final h1
  float*    ln    = h1f + VEC;                  // B*E fp32

  (void)hipMemsetAsync(d_ws, 0, 16384, stream); // reset flags + go lines

  void* args[] = {(void*)&idx,(void*)&wte,(void*)&Wih,(void*)&bih,
                  (void*)&Whh,(void*)&bhh,(void*)&h0g,(void*)&h1g,
                  (void*)&h1f,(void*)&flags,(void*)&go};
  (void)hipLaunchCooperativeKernel((void*)gru_scan, dim3(NBK), dim3(512), args, 0, stream);

  finalize_ln<<<1, 256, 0, stream>>>(h1f, g, ln);
  lm_head<<<786, 256, 0, stream>>>(ln, wte, out);
}